// Round 18
// baseline (97.003 us; speedup 1.0000x reference)
//
#include <hip/hip_runtime.h>
#include <stdint.h>

typedef unsigned short u16;
typedef __attribute__((ext_vector_type(8))) short short8;
typedef __attribute__((ext_vector_type(4))) float f32x4;
typedef __attribute__((ext_vector_type(16))) float f32x16;

#define MFMA __builtin_amdgcn_mfma_f32_16x16x32_bf16
#define MFMA32 __builtin_amdgcn_mfma_f32_32x32x16_bf16

__device__ __forceinline__ u16 f2bf(float f) {
  union { float f; uint32_t u; } v; v.f = f;
  return (u16)((v.u + 0x7FFFu + ((v.u >> 16) & 1u)) >> 16);
}

#define GLOAD16(gp, lp) \
  __builtin_amdgcn_global_load_lds((const __attribute__((address_space(1))) uint32_t*)(gp), \
                                   (__attribute__((address_space(3))) uint32_t*)(lp), 16, 0, 0)

// ws layout (bytes)
#define WS_H    0          // u16 H[64][8][9216]  per-(kt,b) contiguous fragments (9,437,184 B)
                           //   per (kt,b): m1 32x32-B frags [cb0..3][ks0..3]*512 + m2 16x16-B [kf0,1]*512
#define WS_Q1   9502720    // f32 q1[128]
#define WS_Q2   9503232    // f32 q2[128]
#define WS_M1P  9503744    // u64 m1p[64][4096]   (TRANSPOSED: [kt][row])
#define WS_M2P  11600896   // u64 m2p[64][4096]
#define WS_RS1  13698048   // f32 rs1[4096]
#define WS_RS2  13714432   // f32 rs2[4096]
#define WS_WSB  13730816   // u16 wsb[16][144][8] blocked B operand (36,864 B)

// ---------------- kernel 0: fused kmask (blocks 0-1023) + kprep (blocks 1024-1087) ----------------
__global__ __launch_bounds__(256) void k0(const int* __restrict__ sp,
                                          unsigned long long* __restrict__ m1p,
                                          unsigned long long* __restrict__ m2p,
                                          float* __restrict__ rs1, float* __restrict__ rs2,
                                          const float* __restrict__ W1, const float* __restrict__ Wb,
                                          const float* __restrict__ b1, const float* __restrict__ b2,
                                          const float* __restrict__ W2,
                                          float* __restrict__ q1, float* __restrict__ q2,
                                          u16* __restrict__ wsbg) {
  const int tid = threadIdx.x;
  if (blockIdx.x < 1024) {
    int wave = tid >> 6, lane = tid & 63;
    int i = blockIdx.x * 4 + wave;
    const int* rowp = sp + (size_t)i * 4096;
    int c1 = 0, c2 = 0;
    for (int w = 0; w < 64; ++w) {
      int v = rowp[w * 64 + lane];
      unsigned long long bb1 = __ballot(v <= 1);
      unsigned long long bb2 = __ballot(v == 2);
      if (lane == 0) {
        m1p[(size_t)w * 4096 + i] = bb1;
        m2p[(size_t)w * 4096 + i] = bb2;
        c1 += __popcll(bb1);
        c2 += __popcll(bb2);
      }
    }
    if (lane == 0) { rs1[i] = (float)c1; rs2[i] = (float)c2; }
    return;
  }
  int idx = (int)(blockIdx.x - 1024) * 256 + tid;   // 0..16383
  int a = idx >> 7, c = idx & 127;
  float acc = 0.f;
  for (int k = 0; k < 128; ++k) acc += W1[a * 128 + k] * Wb[k * 128 + c];
  wsbg[(((a >> 3) * 144) + c) * 8 + (a & 7)] = f2bf(acc);
  if (idx < 2048) {
    int k = idx >> 4, nn2 = idx & 15;
    wsbg[(((k >> 3) * 144) + 128 + nn2) * 8 + (k & 7)] = f2bf(W2[k * 16 + nn2]);
  }
  if (idx < 128) {
    float s1 = 0.f, s2 = 0.f;
    for (int k = 0; k < 128; ++k) s1 += b1[k] * Wb[k * 128 + idx];
    for (int k = 0; k < 16; ++k)  s2 += b2[k] * Wb[(128 + k) * 128 + idx];
    q1[idx] = s1; q2[idx] = s2;
  }
}

// ---------------- kernel A': u1h2 -> fragment-major H (32x32 m1 frags + 16x16 m2 frags) ----------------
// grid 512 (b = bid>>6, kt-slab = bid&63), 256 threads, 64 rows/block -> 2 blocks/CU.
__global__ __launch_bounds__(256, 2) void kproj(const float* __restrict__ x,
                                                const u16* __restrict__ wsbg,
                                                u16* __restrict__ H) {
  __shared__ u16 wsb[18432];              // blocked B operand (36 KB)
  __shared__ u16 xs[64 * 136];            // x rows bf16 (17.4 KB)
  __shared__ u16 hs[64 * 146];            // result staging (18.7 KB)
  const int tid = threadIdx.x;
  const int bid = blockIdx.x;
  const int b = bid >> 6;
  const int kt = bid & 63;
  const size_t r0 = (size_t)b * 4096 + (size_t)kt * 64;

#pragma unroll
  for (int i = 0; i < 9; ++i)
    GLOAD16(wsbg + (i * 256 + tid) * 8, (char*)&wsb[0] + (i * 256 + tid) * 16);
  {
    const float* xp = x + (r0 + (tid >> 2)) * 128 + (tid & 3) * 32;
    u16* xd = xs + (tid >> 2) * 136 + (tid & 3) * 32;
#pragma unroll
    for (int i = 0; i < 4; ++i) {
      f32x4 a = ((const f32x4*)xp)[i * 2];
      f32x4 bq = ((const f32x4*)xp)[i * 2 + 1];
      short8 pk;
      pk[0] = (short)f2bf(a[0]); pk[1] = (short)f2bf(a[1]);
      pk[2] = (short)f2bf(a[2]); pk[3] = (short)f2bf(a[3]);
      pk[4] = (short)f2bf(bq[0]); pk[5] = (short)f2bf(bq[1]);
      pk[6] = (short)f2bf(bq[2]); pk[7] = (short)f2bf(bq[3]);
      *(short8*)(xd + i * 8) = pk;
    }
  }
  __syncthreads();

  const int w = tid >> 6, l = tid & 63, lr = l & 15, lg = l >> 4;
  f32x4 acc[9];
  f32x4 zz = {0.f, 0.f, 0.f, 0.f};
#pragma unroll
  for (int fn = 0; fn < 9; ++fn) acc[fn] = zz;
#pragma unroll
  for (int kf = 0; kf < 4; ++kf) {
    short8 af = *(const short8*)(xs + (w * 16 + lr) * 136 + kf * 32 + lg * 8);
#pragma unroll
    for (int fn = 0; fn < 9; ++fn) {
      short8 bf = *(const short8*)(wsb + (((kf * 4 + lg) * 144) + fn * 16 + lr) * 8);
      acc[fn] = MFMA(af, bf, acc[fn], 0, 0, 0);
    }
  }
  __syncthreads();
#pragma unroll
  for (int fn = 0; fn < 9; ++fn)
#pragma unroll
    for (int g = 0; g < 4; ++g)
      hs[(w * 16 + lg * 4 + g) * 146 + fn * 16 + lr] = f2bf(acc[fn][g]);
  __syncthreads();
  // scatter to H: m1 as 32x32 B-frags (1024 chunks), m2 as 16x16 B-frags (128 chunks)
  const size_t base = (size_t)kt * 73728 + (size_t)b * 9216;
  for (int i = 0; i < 5; ++i) {
    int ch = i * 256 + tid;
    if (ch < 1152) {
      union { u16 s[8]; uint4 v; } pk;
      size_t di;
      if (ch < 1024) {
        int cb = ch >> 8, ks = (ch >> 6) & 3, ll = ch & 63;
        int row = ks * 16 + (ll >> 5) * 8;      // + e
        int col = cb * 32 + (ll & 31);
#pragma unroll
        for (int e = 0; e < 8; ++e) pk.s[e] = hs[(row + e) * 146 + col];
        di = base + (size_t)((cb * 4 + ks) * 512 + ll * 8);
      } else {
        int c2 = ch - 1024;
        int kf = c2 >> 6, ll = c2 & 63;
        int row = kf * 32 + (ll >> 4) * 8;      // + e
        int col = 128 + (ll & 15);
#pragma unroll
        for (int e = 0; e < 8; ++e) pk.s[e] = hs[(row + e) * 146 + col];
        di = base + (size_t)(8192 + kf * 512 + ll * 8);
      }
      *(uint4*)(H + di) = pk.v;
    }
  }
}

// expand 8 mask bits (shift sh of a 32-bit word) -> 8 bf16 {0,1} packed as short8
__device__ __forceinline__ short8 expand_byte(uint32_t wd, int sh) {
  uint32_t b = (wd >> sh) & 0xFFu;
  uint32_t t = b * 0x8001u;
  union { uint32_t u[4]; short8 s; } r;
  r.u[0] = (t & 0x00010001u) * 0x3F80u;
  r.u[1] = (t & 0x00040004u) * 0x0FE0u;
  r.u[2] = (t & 0x00100010u) * 0x03F8u;
  r.u[3] = (t & 0x00400040u) * 0x00FEu;
  return r.s;
}

// ---------------- kernel B1: (2 rowgroup x 1 colblock)/wave 32x32 retile ----------------
// grid 256 (b=bid&7 XCD-pinned, 128-row panels), 512 thr = 8 waves (h2 = w>>2, cb = w&3).
// wave: m1 rowgroups {2h2,2h2+1} x colblock cb: 8 MFMA32/kt, B-frags read ONCE (4 reads, reuse x2).
//       m2 kf=h2, row-tiles {2cb,2cb+1}: 2 MFMA16/kt (1 B-frag); kf-partials combined in epilogue.
// Per wave/kt ds: 5 b128 + 2 b64 + 2 b32 -> 52 KB/CU/kt (was 92).
__global__ __launch_bounds__(512, 2) void kb1(const u16* __restrict__ H,
                                              const char* __restrict__ M1b,
                                              const char* __restrict__ M2b,
                                              const float* __restrict__ rs1, const float* __restrict__ rs2,
                                              const float* __restrict__ q1, const float* __restrict__ q2,
                                              const float* __restrict__ Wb, const float* __restrict__ bb,
                                              float* __restrict__ out) {
  __shared__ u16 bt[3][9216];              // 3-buffered fragment tile (55.3 KB)
  __shared__ u16 mkb[3][1024];             // 3-buffered mask slab (6 KB): [1024B m1][1024B m2]
  __shared__ float f2pf[2][128][16];       // m2@h2 kf-partials (16 KB)
  __shared__ u16 f2s[128 * 40];            // f2 bf16 (10 KB)
  __shared__ u16 wb2s[2048];               // Wb2 as 32x32 B-frags, K=16 (4 KB)  -> 91.7 KB

  const int tid = threadIdx.x;
  const int bid = blockIdx.x;
  const int b = bid & 7;
  const int i0 = (bid >> 3) * 128;

  const int w = tid >> 6, l = tid & 63, lr = l & 15, lg = l >> 4;
  const int h2 = w >> 2, cb = w & 3;
  const int rg0 = h2 * 2, rg1 = h2 * 2 + 1;
  const int kfm = h2;                       // m2 kf
  const int rt0 = cb * 2, rt1 = cb * 2 + 1; // m2 row-tiles (16 rows each)
  const int sh32 = (l >> 5) * 8;            // 32x32 A-operand k-half shift
  const int lgsh = lg * 8;                  // 16x16 A-operand shift

  // stage pointers: per (kt,b) block is CONTIGUOUS 9216 u16 at H + kt*73728 + b*9216
  const u16* pB0 = H + (size_t)b * 9216 + (size_t)tid * 8;
  const u16* pB1 = H + (size_t)b * 9216 + (size_t)(512 + tid) * 8;
  const u16* pB2 = H + (size_t)b * 9216 + (size_t)(1024 + tid) * 8;  // used tid<128
  const int mc = tid - 128;                                          // tid in [128,256)
  const char* pM = ((mc & 64) ? M2b : M1b) + (size_t)i0 * 8 + (size_t)(mc & 63) * 16;
  const int dB0 = tid * 16, dB1 = (512 + tid) * 16, dB2 = (1024 + tid) * 16;
  const int dM = ((mc >> 6) & 1) * 1024 + (mc & 63) * 16;

#define STAGE(BUF) { \
    GLOAD16(pB0, (char*)&bt[BUF][0] + dB0); \
    GLOAD16(pB1, (char*)&bt[BUF][0] + dB1); \
    if (tid < 128) GLOAD16(pB2, (char*)&bt[BUF][0] + dB2); \
    else if (tid < 256) GLOAD16(pM, (char*)&mkb[BUF][0] + dM); \
    pB0 += 73728; pB1 += 73728; pB2 += 73728; pM += 32768; }

  // fragment offsets (u16): m1 (cb,ks) at (cb*4+ks)*512; m2 kf at 8192+kf*512
  const int fb0 = (cb * 4) * 512 + l * 8;
  const int fm0 = 8192 + kfm * 512 + l * 8;

  f32x16 am0, am1;
  f32x4 acc2a, acc2b;
#pragma unroll
  for (int i = 0; i < 16; ++i) { am0[i] = 0.f; am1[i] = 0.f; }
  acc2a[0] = acc2a[1] = acc2a[2] = acc2a[3] = 0.f;
  acc2b[0] = acc2b[1] = acc2b[2] = acc2b[3] = 0.f;

#define WAITV { if (w < 4) asm volatile("s_waitcnt vmcnt(3)" ::: "memory"); \
                else asm volatile("s_waitcnt vmcnt(2)" ::: "memory"); }

#define COMPUTE(BUF) { \
    const u16* src_ = &bt[BUF][0]; \
    const char* mk_ = (const char*)&mkb[BUF][0]; \
    uint2 cA_ = *(const uint2*)(mk_ + (rg0 * 32 + (l & 31)) * 8); \
    uint2 cB_ = *(const uint2*)(mk_ + (rg1 * 32 + (l & 31)) * 8); \
    uint32_t cm0_ = *(const uint32_t*)(mk_ + 1024 + (rt0 * 16 + lr) * 8 + kfm * 4); \
    uint32_t cm1_ = *(const uint32_t*)(mk_ + 1024 + (rt1 * 16 + lr) * 8 + kfm * 4); \
    short8 bf0_ = *(const short8*)(src_ + fb0); \
    short8 bf1_ = *(const short8*)(src_ + fb0 + 512); \
    short8 bf2_ = *(const short8*)(src_ + fb0 + 1024); \
    short8 bf3_ = *(const short8*)(src_ + fb0 + 1536); \
    short8 bm_  = *(const short8*)(src_ + fm0); \
    short8 eA0_ = expand_byte(cA_.x, sh32); \
    short8 eA1_ = expand_byte(cA_.x, sh32 + 16); \
    short8 eA2_ = expand_byte(cA_.y, sh32); \
    short8 eA3_ = expand_byte(cA_.y, sh32 + 16); \
    short8 eB0_ = expand_byte(cB_.x, sh32); \
    short8 eB1_ = expand_byte(cB_.x, sh32 + 16); \
    short8 eB2_ = expand_byte(cB_.y, sh32); \
    short8 eB3_ = expand_byte(cB_.y, sh32 + 16); \
    short8 em0_ = expand_byte(cm0_, lgsh); \
    short8 em1_ = expand_byte(cm1_, lgsh); \
    __builtin_amdgcn_s_setprio(1); \
    am0 = MFMA32(eA0_, bf0_, am0, 0, 0, 0); \
    am1 = MFMA32(eB0_, bf0_, am1, 0, 0, 0); \
    am0 = MFMA32(eA1_, bf1_, am0, 0, 0, 0); \
    am1 = MFMA32(eB1_, bf1_, am1, 0, 0, 0); \
    am0 = MFMA32(eA2_, bf2_, am0, 0, 0, 0); \
    am1 = MFMA32(eB2_, bf2_, am1, 0, 0, 0); \
    am0 = MFMA32(eA3_, bf3_, am0, 0, 0, 0); \
    am1 = MFMA32(eB3_, bf3_, am1, 0, 0, 0); \
    acc2a = MFMA(em0_, bm_, acc2a, 0, 0, 0); \
    acc2b = MFMA(em1_, bm_, acc2b, 0, 0, 0); \
    __builtin_amdgcn_s_setprio(0); }

#define PHASE(BUF, BUF2) { WAITV; __builtin_amdgcn_s_barrier(); STAGE(BUF2); COMPUTE(BUF) }

  // prologue: stage kt=0,1
  STAGE(0);
  STAGE(1);

  // stage Wb2 as 32x32 B-frags: frag cb, lane ll, elem e = Wb[(128 + (ll>>5)*8+e)*128 + cb*32+(ll&31)]
#pragma unroll
  for (int i = 0; i < 4; ++i) {
    int e = i * 512 + tid;                 // 2048 u16
    int cbw = e >> 9, rem = e & 511, ll = rem >> 3, ee = rem & 7;
    wb2s[e] = f2bf(Wb[(128 + (ll >> 5) * 8 + ee) * 128 + cbw * 32 + (ll & 31)]);
  }

  for (int it = 0; it < 20; ++it) {        // phases 0..59
    PHASE(0, 2);
    PHASE(1, 0);
    PHASE(2, 1);
  }
  PHASE(0, 2);                             // phase 60 (stages kt 62)
  PHASE(1, 0);                             // phase 61 (stages kt 63)
  { WAITV; __builtin_amdgcn_s_barrier(); COMPUTE(2) }                          // phase 62
  { asm volatile("s_waitcnt vmcnt(0)" ::: "memory");
    __builtin_amdgcn_s_barrier(); COMPUTE(0) }                                 // phase 63

  // epilogue: m2 kf-partials -> f2pf, combine -> f2s (16x16 C layout)
#pragma unroll
  for (int gg = 0; gg < 4; ++gg) {
    f2pf[kfm][rt0 * 16 + lg * 4 + gg][lr] = acc2a[gg];
    f2pf[kfm][rt1 * 16 + lg * 4 + gg][lr] = acc2b[gg];
  }
  __syncthreads();
#pragma unroll
  for (int j = 0; j < 4; ++j) {
    int e = j * 512 + tid;                 // 128x16 = 2048 elems
    int row = e >> 4, col = e & 15;
    f2s[row * 40 + col] = f2bf(f2pf[0][row][col] + f2pf[1][row][col]);
  }
  __syncthreads();

  // epilogue MFMA32: am += f2frag(rowgroup) x Wb2frag(cb), K=16 exact
  {
    short8 bw_ = *(const short8*)(wb2s + cb * 512 + l * 8);
    short8 afA = *(const short8*)(f2s + (rg0 * 32 + (l & 31)) * 40 + sh32);
    short8 afB = *(const short8*)(f2s + (rg1 * 32 + (l & 31)) * 40 + sh32);
    am0 = MFMA32(afA, bw_, am0, 0, 0, 0);
    am1 = MFMA32(afB, bw_, am1, 0, 0, 0);
  }

  // final: + rs1*q1 + rs2*q2 + bb, store f32. 32x32 C: col=l&31, row=(r&3)+8*(r>>2)+4*(l>>5)
  const int colA = cb * 32 + (l & 31);
  const float q1v = q1[colA], q2v = q2[colA], bbv = bb[colA];
#pragma unroll
  for (int r = 0; r < 16; ++r) {
    int rr = (r & 3) + 8 * (r >> 2) + 4 * (l >> 5);
    {
      int row = rg0 * 32 + rr;
      float r1 = rs1[i0 + row], r2 = rs2[i0 + row];
      out[((size_t)b * 4096 + i0 + row) * 128 + colA] = am0[r] + r1 * q1v + r2 * q2v + bbv;
    }
    {
      int row = rg1 * 32 + rr;
      float r1 = rs1[i0 + row], r2 = rs2[i0 + row];
      out[((size_t)b * 4096 + i0 + row) * 128 + colA] = am1[r] + r1 * q1v + r2 * q2v + bbv;
    }
  }
}

extern "C" void kernel_launch(void* const* d_in, const int* in_sizes, int n_in,
                              void* d_out, int out_size, void* d_ws, size_t ws_size,
                              hipStream_t stream) {
  const float* x  = (const float*)d_in[0];
  const int*   sp = (const int*)d_in[1];
  const float* W1 = (const float*)d_in[2];
  const float* b1 = (const float*)d_in[3];
  const float* W2 = (const float*)d_in[4];
  const float* b2 = (const float*)d_in[5];
  const float* Wb = (const float*)d_in[6];
  const float* bb = (const float*)d_in[7];
  float* out = (float*)d_out;
  char* ws = (char*)d_ws;

  u16* H = (u16*)(ws + WS_H);
  float* q1 = (float*)(ws + WS_Q1);
  float* q2 = (float*)(ws + WS_Q2);
  unsigned long long* m1p = (unsigned long long*)(ws + WS_M1P);
  unsigned long long* m2p = (unsigned long long*)(ws + WS_M2P);
  float* rs1 = (float*)(ws + WS_RS1);
  float* rs2 = (float*)(ws + WS_RS2);
  u16* wsbg = (u16*)(ws + WS_WSB);

  k0<<<1088, 256, 0, stream>>>(sp, m1p, m2p, rs1, rs2, W1, Wb, b1, b2, W2, q1, q2, wsbg);
  kproj<<<512, 256, 0, stream>>>(x, wsbg, H);
  kb1<<<256, 512, 0, stream>>>(H, (const char*)m1p, (const char*)m2p,
                               rs1, rs2, q1, q2, Wb, bb, out);
}

// Round 20
// 88.461 us; speedup vs baseline: 1.0966x; 1.0966x over previous
//
#include <hip/hip_runtime.h>
#include <stdint.h>

typedef unsigned short u16;
typedef __attribute__((ext_vector_type(8))) short short8;
typedef __attribute__((ext_vector_type(4))) float f32x4;
typedef __attribute__((ext_vector_type(16))) float f32x16;

#define MFMA __builtin_amdgcn_mfma_f32_16x16x32_bf16
#define MFMA32 __builtin_amdgcn_mfma_f32_32x32x16_bf16

__device__ __forceinline__ u16 f2bf(float f) {
  union { float f; uint32_t u; } v; v.f = f;
  return (u16)((v.u + 0x7FFFu + ((v.u >> 16) & 1u)) >> 16);
}

#define GLOAD16(gp, lp) \
  __builtin_amdgcn_global_load_lds((const __attribute__((address_space(1))) uint32_t*)(gp), \
                                   (__attribute__((address_space(3))) uint32_t*)(lp), 16, 0, 0)

// ws layout (bytes)
#define WS_H    0          // u16 H[64][8][9216]  per-(kt,b) contiguous fragments (9,437,184 B)
#define WS_Q1   9502720    // f32 q1[128]
#define WS_Q2   9503232    // f32 q2[128]
#define WS_M1P  9503744    // u64 m1p[64][4096]   (TRANSPOSED: [kt][row])
#define WS_M2P  11600896   // u64 m2p[64][4096]
#define WS_RS1  13698048   // f32 rs1[4096]
#define WS_RS2  13714432   // f32 rs2[4096]
#define WS_WSB  13730816   // u16 wsb[16][144][8] blocked B operand (36,864 B)

// ---------------- kernel 0: fused kmask (blocks 0-1023) + kprep (blocks 1024-1087) ----------------
__global__ __launch_bounds__(256) void k0(const int* __restrict__ sp,
                                          unsigned long long* __restrict__ m1p,
                                          unsigned long long* __restrict__ m2p,
                                          float* __restrict__ rs1, float* __restrict__ rs2,
                                          const float* __restrict__ W1, const float* __restrict__ Wb,
                                          const float* __restrict__ b1, const float* __restrict__ b2,
                                          const float* __restrict__ W2,
                                          float* __restrict__ q1, float* __restrict__ q2,
                                          u16* __restrict__ wsbg) {
  const int tid = threadIdx.x;
  if (blockIdx.x < 1024) {
    int wave = tid >> 6, lane = tid & 63;
    int i = blockIdx.x * 4 + wave;
    const int* rowp = sp + (size_t)i * 4096;
    int c1 = 0, c2 = 0;
    for (int w = 0; w < 64; ++w) {
      int v = rowp[w * 64 + lane];
      unsigned long long bb1 = __ballot(v <= 1);
      unsigned long long bb2 = __ballot(v == 2);
      if (lane == 0) {
        m1p[(size_t)w * 4096 + i] = bb1;
        m2p[(size_t)w * 4096 + i] = bb2;
        c1 += __popcll(bb1);
        c2 += __popcll(bb2);
      }
    }
    if (lane == 0) { rs1[i] = (float)c1; rs2[i] = (float)c2; }
    return;
  }
  int idx = (int)(blockIdx.x - 1024) * 256 + tid;   // 0..16383
  int a = idx >> 7, c = idx & 127;
  float acc = 0.f;
  for (int k = 0; k < 128; ++k) acc += W1[a * 128 + k] * Wb[k * 128 + c];
  wsbg[(((a >> 3) * 144) + c) * 8 + (a & 7)] = f2bf(acc);
  if (idx < 2048) {
    int k = idx >> 4, nn2 = idx & 15;
    wsbg[(((k >> 3) * 144) + 128 + nn2) * 8 + (k & 7)] = f2bf(W2[k * 16 + nn2]);
  }
  if (idx < 128) {
    float s1 = 0.f, s2 = 0.f;
    for (int k = 0; k < 128; ++k) s1 += b1[k] * Wb[k * 128 + idx];
    for (int k = 0; k < 16; ++k)  s2 += b2[k] * Wb[(128 + k) * 128 + idx];
    q1[idx] = s1; q2[idx] = s2;
  }
}

// ---------------- kernel A': u1h2 -> fragment-major H (32x32 m1 frags + 16x16 m2 frags) ----------------
// grid 512 (b = bid>>6, kt-slab = bid&63), 256 threads, 64 rows/block -> 2 blocks/CU.
__global__ __launch_bounds__(256, 2) void kproj(const float* __restrict__ x,
                                                const u16* __restrict__ wsbg,
                                                u16* __restrict__ H) {
  __shared__ u16 wsb[18432];              // blocked B operand (36 KB)
  __shared__ u16 xs[64 * 136];            // x rows bf16 (17.4 KB)
  __shared__ u16 hs[64 * 146];            // result staging (18.7 KB)
  const int tid = threadIdx.x;
  const int bid = blockIdx.x;
  const int b = bid >> 6;
  const int kt = bid & 63;
  const size_t r0 = (size_t)b * 4096 + (size_t)kt * 64;

#pragma unroll
  for (int i = 0; i < 9; ++i)
    GLOAD16(wsbg + (i * 256 + tid) * 8, (char*)&wsb[0] + (i * 256 + tid) * 16);
  {
    const float* xp = x + (r0 + (tid >> 2)) * 128 + (tid & 3) * 32;
    u16* xd = xs + (tid >> 2) * 136 + (tid & 3) * 32;
#pragma unroll
    for (int i = 0; i < 4; ++i) {
      f32x4 a = ((const f32x4*)xp)[i * 2];
      f32x4 bq = ((const f32x4*)xp)[i * 2 + 1];
      short8 pk;
      pk[0] = (short)f2bf(a[0]); pk[1] = (short)f2bf(a[1]);
      pk[2] = (short)f2bf(a[2]); pk[3] = (short)f2bf(a[3]);
      pk[4] = (short)f2bf(bq[0]); pk[5] = (short)f2bf(bq[1]);
      pk[6] = (short)f2bf(bq[2]); pk[7] = (short)f2bf(bq[3]);
      *(short8*)(xd + i * 8) = pk;
    }
  }
  __syncthreads();

  const int w = tid >> 6, l = tid & 63, lr = l & 15, lg = l >> 4;
  f32x4 acc[9];
  f32x4 zz = {0.f, 0.f, 0.f, 0.f};
#pragma unroll
  for (int fn = 0; fn < 9; ++fn) acc[fn] = zz;
#pragma unroll
  for (int kf = 0; kf < 4; ++kf) {
    short8 af = *(const short8*)(xs + (w * 16 + lr) * 136 + kf * 32 + lg * 8);
#pragma unroll
    for (int fn = 0; fn < 9; ++fn) {
      short8 bf = *(const short8*)(wsb + (((kf * 4 + lg) * 144) + fn * 16 + lr) * 8);
      acc[fn] = MFMA(af, bf, acc[fn], 0, 0, 0);
    }
  }
  __syncthreads();
#pragma unroll
  for (int fn = 0; fn < 9; ++fn)
#pragma unroll
    for (int g = 0; g < 4; ++g)
      hs[(w * 16 + lg * 4 + g) * 146 + fn * 16 + lr] = f2bf(acc[fn][g]);
  __syncthreads();
  // scatter to H: m1 as 32x32 B-frags (1024 chunks), m2 as 16x16 B-frags (128 chunks)
  const size_t base = (size_t)kt * 73728 + (size_t)b * 9216;
  for (int i = 0; i < 5; ++i) {
    int ch = i * 256 + tid;
    if (ch < 1152) {
      union { u16 s[8]; uint4 v; } pk;
      size_t di;
      if (ch < 1024) {
        int cb = ch >> 8, ks = (ch >> 6) & 3, ll = ch & 63;
        int row = ks * 16 + (ll >> 5) * 8;      // + e
        int col = cb * 32 + (ll & 31);
#pragma unroll
        for (int e = 0; e < 8; ++e) pk.s[e] = hs[(row + e) * 146 + col];
        di = base + (size_t)((cb * 4 + ks) * 512 + ll * 8);
      } else {
        int c2 = ch - 1024;
        int kf = c2 >> 6, ll = c2 & 63;
        int row = kf * 32 + (ll >> 4) * 8;      // + e
        int col = 128 + (ll & 15);
#pragma unroll
        for (int e = 0; e < 8; ++e) pk.s[e] = hs[(row + e) * 146 + col];
        di = base + (size_t)(8192 + kf * 512 + ll * 8);
      }
      *(uint4*)(H + di) = pk.v;
    }
  }
}

// expand 8 mask bits (shift sh of a 32-bit word) -> 8 bf16 {0,1} packed as short8
__device__ __forceinline__ short8 expand_byte(uint32_t wd, int sh) {
  uint32_t b = (wd >> sh) & 0xFFu;
  uint32_t t = b * 0x8001u;
  union { uint32_t u[4]; short8 s; } r;
  r.u[0] = (t & 0x00010001u) * 0x3F80u;
  r.u[1] = (t & 0x00040004u) * 0x0FE0u;
  r.u[2] = (t & 0x00100010u) * 0x03F8u;
  r.u[3] = (t & 0x00400040u) * 0x00FEu;
  return r.s;
}

// ---------------- kernel B1: 64-row panels, 2 blocks/CU (4 waves/SIMD via independent blocks) ----------------
// grid 512 (b=bid&7 XCD-pinned, panel=bid>>3), 512 thr = 8 waves (rg = w>>2, cb = w&3).
// wave: m1 rowgroup rg (32 rows) x colblock cb: 4 MFMA32/kt (4 expands, 4 B-frag b128).
//       m2 (rt=w&3, kf=w>>2): 1 MFMA16/kt; kf-partials combined in epilogue via f2pf.
// LDS 75.7 KB -> 2 blocks/CU; (512,2) = 256-VGPR budget (counted vmcnt REQUIRES spill-free).
__global__ __launch_bounds__(512, 2) void kb1(const u16* __restrict__ H,
                                              const char* __restrict__ M1b,
                                              const char* __restrict__ M2b,
                                              const float* __restrict__ rs1, const float* __restrict__ rs2,
                                              const float* __restrict__ q1, const float* __restrict__ q2,
                                              const float* __restrict__ Wb, const float* __restrict__ bb,
                                              float* __restrict__ out) {
  __shared__ u16 bt[3][9216];              // 3-buffered fragment tile (55.3 KB)
  __shared__ u16 mkb[3][1024];             // 3-buffered mask slab (6 KB): [512B m1][512B m2] x2 pad
  __shared__ float f2pf[2][64][16];        // m2 kf-partials (8 KB)
  __shared__ u16 f2s[64 * 40];             // f2 bf16 (5 KB)
  __shared__ u16 wb2s[2048];               // Wb2 as 32x32 B-frags, K=16 (4 KB)  -> 78.3 KB

  const int tid = threadIdx.x;
  const int bid = blockIdx.x;
  const int b = bid & 7;
  const int i0 = (bid >> 3) * 64;

  const int w = tid >> 6, l = tid & 63, lr = l & 15, lg = l >> 4;
  const int rg = w >> 2, cb = w & 3;
  const int rt = w & 3, kfm = w >> 2;       // m2 row-tile / kf
  const int sh32 = (l >> 5) * 8;            // 32x32 A-operand k-half shift
  const int lgsh = lg * 8;                  // 16x16 A-operand shift

  // stage pointers: per (kt,b) block is CONTIGUOUS 9216 u16 at H + kt*73728 + b*9216
  const u16* pB0 = H + (size_t)b * 9216 + (size_t)tid * 8;           // chunks 0..511
  const u16* pB1 = H + (size_t)b * 9216 + (size_t)(512 + tid) * 8;   // chunks 512..1023
  const u16* pB2 = H + (size_t)b * 9216 + (size_t)(1024 + tid) * 8;  // chunks 1024..1151 (tid<128)
  const int mc = tid - 128;                                          // tid in [128,192): mask chunks
  const char* pM = ((mc < 32) ? M1b : M2b) + (size_t)i0 * 8 + (size_t)(mc & 31) * 16;
  const int dB0 = tid * 16, dB1 = (512 + tid) * 16, dB2 = (1024 + tid) * 16;
  const int dM = mc * 16;                   // m1 bytes 0..511, m2 bytes 512..1023

#define STAGE(BUF) { \
    GLOAD16(pB0, (char*)&bt[BUF][0] + dB0); \
    GLOAD16(pB1, (char*)&bt[BUF][0] + dB1); \
    if (tid < 128) GLOAD16(pB2, (char*)&bt[BUF][0] + dB2); \
    else if (tid < 192) GLOAD16(pM, (char*)&mkb[BUF][0] + dM); \
    pB0 += 73728; pB1 += 73728; pB2 += 73728; pM += 32768; }

  // fragment offsets (u16): m1 (cb,ks) at (cb*4+ks)*512; m2 kf at 8192+kf*512
  const int fb0 = (cb * 4) * 512 + l * 8;
  const int fm0 = 8192 + kfm * 512 + l * 8;

  f32x16 am;
  f32x4 acc2;
#pragma unroll
  for (int i = 0; i < 16; ++i) am[i] = 0.f;
  acc2[0] = acc2[1] = acc2[2] = acc2[3] = 0.f;

#define WAITV { if (w < 3) asm volatile("s_waitcnt vmcnt(3)" ::: "memory"); \
                else asm volatile("s_waitcnt vmcnt(2)" ::: "memory"); }

#define COMPUTE(BUF) { \
    const u16* src_ = &bt[BUF][0]; \
    const char* mk_ = (const char*)&mkb[BUF][0]; \
    uint2 cA_ = *(const uint2*)(mk_ + (rg * 32 + (l & 31)) * 8); \
    uint32_t cm_ = *(const uint32_t*)(mk_ + 512 + (rt * 16 + lr) * 8 + kfm * 4); \
    short8 bf0_ = *(const short8*)(src_ + fb0); \
    short8 bf1_ = *(const short8*)(src_ + fb0 + 512); \
    short8 bf2_ = *(const short8*)(src_ + fb0 + 1024); \
    short8 bf3_ = *(const short8*)(src_ + fb0 + 1536); \
    short8 bm_  = *(const short8*)(src_ + fm0); \
    short8 e0_ = expand_byte(cA_.x, sh32); \
    short8 e1_ = expand_byte(cA_.x, sh32 + 16); \
    short8 e2_ = expand_byte(cA_.y, sh32); \
    short8 e3_ = expand_byte(cA_.y, sh32 + 16); \
    short8 em_ = expand_byte(cm_, lgsh); \
    __builtin_amdgcn_s_setprio(1); \
    am = MFMA32(e0_, bf0_, am, 0, 0, 0); \
    am = MFMA32(e1_, bf1_, am, 0, 0, 0); \
    am = MFMA32(e2_, bf2_, am, 0, 0, 0); \
    am = MFMA32(e3_, bf3_, am, 0, 0, 0); \
    acc2 = MFMA(em_, bm_, acc2, 0, 0, 0); \
    __builtin_amdgcn_s_setprio(0); }

#define PHASE(BUF, BUF2) { WAITV; __builtin_amdgcn_s_barrier(); STAGE(BUF2); COMPUTE(BUF) }

  // prologue: stage kt=0,1
  STAGE(0);
  STAGE(1);

  // stage Wb2 as 32x32 B-frags: frag cb, lane ll, elem e = Wb[(128 + (ll>>5)*8+e)*128 + cb*32+(ll&31)]
#pragma unroll
  for (int i = 0; i < 4; ++i) {
    int e = i * 512 + tid;                 // 2048 u16
    int cbw = e >> 9, rem = e & 511, ll = rem >> 3, ee = rem & 7;
    wb2s[e] = f2bf(Wb[(128 + (ll >> 5) * 8 + ee) * 128 + cbw * 32 + (ll & 31)]);
  }

  for (int it = 0; it < 20; ++it) {        // phases 0..59
    PHASE(0, 2);
    PHASE(1, 0);
    PHASE(2, 1);
  }
  PHASE(0, 2);                             // phase 60 (stages kt 62)
  PHASE(1, 0);                             // phase 61 (stages kt 63)
  { WAITV; __builtin_amdgcn_s_barrier(); COMPUTE(2) }                          // phase 62
  { asm volatile("s_waitcnt vmcnt(0)" ::: "memory");
    __builtin_amdgcn_s_barrier(); COMPUTE(0) }                                 // phase 63

  // epilogue: m2 kf-partials -> f2pf, combine -> f2s (16x16 C layout)
#pragma unroll
  for (int gg = 0; gg < 4; ++gg)
    f2pf[kfm][rt * 16 + lg * 4 + gg][lr] = acc2[gg];
  __syncthreads();
#pragma unroll
  for (int j = 0; j < 2; ++j) {
    int e = j * 512 + tid;                 // 64x16 = 1024 elems
    int row = e >> 4, col = e & 15;
    f2s[row * 40 + col] = f2bf(f2pf[0][row][col] + f2pf[1][row][col]);
  }
  __syncthreads();

  // epilogue MFMA32: am += f2frag(rowgroup rg) x Wb2frag(cb), K=16 exact
  {
    short8 bw_ = *(const short8*)(wb2s + cb * 512 + l * 8);
    short8 af_ = *(const short8*)(f2s + (rg * 32 + (l & 31)) * 40 + sh32);
    am = MFMA32(af_, bw_, am, 0, 0, 0);
  }

  // final: + rs1*q1 + rs2*q2 + bb, store f32. 32x32 C: col=l&31, row=(r&3)+8*(r>>2)+4*(l>>5)
  const int colA = cb * 32 + (l & 31);
  const float q1v = q1[colA], q2v = q2[colA], bbv = bb[colA];
#pragma unroll
  for (int r = 0; r < 16; ++r) {
    int row = rg * 32 + (r & 3) + 8 * (r >> 2) + 4 * (l >> 5);
    float r1 = rs1[i0 + row], r2 = rs2[i0 + row];
    out[((size_t)b * 4096 + i0 + row) * 128 + colA] = am[r] + r1 * q1v + r2 * q2v + bbv;
  }
}

extern "C" void kernel_launch(void* const* d_in, const int* in_sizes, int n_in,
                              void* d_out, int out_size, void* d_ws, size_t ws_size,
                              hipStream_t stream) {
  const float* x  = (const float*)d_in[0];
  const int*   sp = (const int*)d_in[1];
  const float* W1 = (const float*)d_in[2];
  const float* b1 = (const float*)d_in[3];
  const float* W2 = (const float*)d_in[4];
  const float* b2 = (const float*)d_in[5];
  const float* Wb = (const float*)d_in[6];
  const float* bb = (const float*)d_in[7];
  float* out = (float*)d_out;
  char* ws = (char*)d_ws;

  u16* H = (u16*)(ws + WS_H);
  float* q1 = (float*)(ws + WS_Q1);
  float* q2 = (float*)(ws + WS_Q2);
  unsigned long long* m1p = (unsigned long long*)(ws + WS_M1P);
  unsigned long long* m2p = (unsigned long long*)(ws + WS_M2P);
  float* rs1 = (float*)(ws + WS_RS1);
  float* rs2 = (float*)(ws + WS_RS2);
  u16* wsbg = (u16*)(ws + WS_WSB);

  k0<<<1088, 256, 0, stream>>>(sp, m1p, m2p, rs1, rs2, W1, Wb, b1, b2, W2, q1, q2, wsbg);
  kproj<<<512, 256, 0, stream>>>(x, wsbg, H);
  kb1<<<512, 512, 0, stream>>>(H, (const char*)m1p, (const char*)m2p,
                               rs1, rs2, q1, q2, Wb, bb, out);
}